// Round 8
// baseline (1737.971 us; speedup 1.0000x reference)
//
#include <hip/hip_runtime.h>
#include <hip/hip_bf16.h>
#include <math.h>

#define N_TX   100000
#define N_USER 50000
#define F_TX   128
#define F_USER 64
#define HID    64
#define NH     4
#define OUTC   32
#define NE     500000
#define HC1    256          // NH*HID
#define SLOPE  0.2f
#define NB_T   391          // (N_TX+255)/256
#define NB_U   196          // (N_USER+255)/256

__device__ __forceinline__ float elu_f(float x) { return x > 0.f ? x : (expf(x) - 1.f); }
__device__ __forceinline__ float lrelu_exp(float x) { x = x > 0.f ? x : SLOPE * x; return expf(x); }

// full-wave sum via xor butterfly (all lanes end with the total)
__device__ __forceinline__ float wave_sum(float s)
{
    s += __shfl_xor(s, 32); s += __shfl_xor(s, 16); s += __shfl_xor(s, 8);
    s += __shfl_xor(s, 4);  s += __shfl_xor(s, 2);  s += __shfl_xor(s, 1);
    return s;
}

// reduce 8 values across the wave with 27 shuffles; lane 8k stores value k.
__device__ __forceinline__ void reduce8_store(
    float p0, float p1, float p2, float p3, float p4, float p5, float p6, float p7,
    int lane, float* __restrict__ oa, float* __restrict__ ob)
{
    p0 += __shfl_xor(p0, 32); p0 += __shfl_xor(p0, 16); p0 += __shfl_xor(p0, 8);
    p1 += __shfl_xor(p1, 32); p1 += __shfl_xor(p1, 16); p1 += __shfl_xor(p1, 8);
    p2 += __shfl_xor(p2, 32); p2 += __shfl_xor(p2, 16); p2 += __shfl_xor(p2, 8);
    p3 += __shfl_xor(p3, 32); p3 += __shfl_xor(p3, 16); p3 += __shfl_xor(p3, 8);
    p4 += __shfl_xor(p4, 32); p4 += __shfl_xor(p4, 16); p4 += __shfl_xor(p4, 8);
    p5 += __shfl_xor(p5, 32); p5 += __shfl_xor(p5, 16); p5 += __shfl_xor(p5, 8);
    p6 += __shfl_xor(p6, 32); p6 += __shfl_xor(p6, 16); p6 += __shfl_xor(p6, 8);
    p7 += __shfl_xor(p7, 32); p7 += __shfl_xor(p7, 16); p7 += __shfl_xor(p7, 8);
    int g = lane >> 3;
    float s = p0;
    s = (g == 1) ? p1 : s; s = (g == 2) ? p2 : s; s = (g == 3) ? p3 : s;
    s = (g == 4) ? p4 : s; s = (g == 5) ? p5 : s; s = (g == 6) ? p6 : s;
    s = (g == 7) ? p7 : s;
    s += __shfl_xor(s, 4); s += __shfl_xor(s, 2); s += __shfl_xor(s, 1);
    if ((lane & 7) == 0) {
        if (g < 4) oa[g] = s;
        else       ob[g - 4] = s;
    }
}

// ---- named-register W tiles (SSA values the compiler cannot demote) ----
#define WDECL16 \
    const float4 WW0=Wc[0],WW1=Wc[1],WW2=Wc[2],WW3=Wc[3],WW4=Wc[4],WW5=Wc[5],WW6=Wc[6],WW7=Wc[7], \
                 WW8=Wc[8],WW9=Wc[9],WW10=Wc[10],WW11=Wc[11],WW12=Wc[12],WW13=Wc[13],WW14=Wc[14],WW15=Wc[15];
#define WDECL32 WDECL16 \
    const float4 WW16=Wc[16],WW17=Wc[17],WW18=Wc[18],WW19=Wc[19],WW20=Wc[20],WW21=Wc[21],WW22=Wc[22],WW23=Wc[23], \
                 WW24=Wc[24],WW25=Wc[25],WW26=Wc[26],WW27=Wc[27],WW28=Wc[28],WW29=Wc[29],WW30=Wc[30],WW31=Wc[31];

#define FS(i, xr) { const float4 x_ = (xr)[i]; \
    a0 = fmaf(x_.x, WW##i.x, a0); a1 = fmaf(x_.y, WW##i.y, a1); \
    a2 = fmaf(x_.z, WW##i.z, a2); a3 = fmaf(x_.w, WW##i.w, a3); }
#define F16(xr) FS(0,xr) FS(1,xr) FS(2,xr) FS(3,xr) FS(4,xr) FS(5,xr) FS(6,xr) FS(7,xr) \
                FS(8,xr) FS(9,xr) FS(10,xr) FS(11,xr) FS(12,xr) FS(13,xr) FS(14,xr) FS(15,xr)
#define F32(xr) F16(xr) FS(16,xr) FS(17,xr) FS(18,xr) FS(19,xr) FS(20,xr) FS(21,xr) FS(22,xr) FS(23,xr) \
                FS(24,xr) FS(25,xr) FS(26,xr) FS(27,xr) FS(28,xr) FS(29,xr) FS(30,xr) FS(31,xr)

// ------------- fold attention vectors into weights: Mv[k,h] = sum_c W[k,h*C+c]*a[h,c] -------------
struct AVArgs  { const float* W; const float* a; float* out; int K; int H; int C; };
struct AVArgs6 { AVArgs t[6]; };

__global__ void attn_vecs_kernel(AVArgs6 args)
{
    AVArgs A = args.t[blockIdx.x];
    int tid = threadIdx.x;
    if (tid < A.K * A.H) {
        int k = tid % A.K, h = tid / A.K;
        float s = 0.f;
        const float* wrow = A.W + (size_t)k * (A.H * A.C) + h * A.C;
        const float* arow = A.a + h * A.C;
        for (int c = 0; c < A.C; ++c) s += wrow[c] * arow[c];
        A.out[k * A.H + h] = s;
    }
}

// ------------- transpose weights into column-contiguous layouts -------------
// out: [0,16384) W1T_u2t[(h*64+j)*64+c] ; [16384,32768) W1T_t2u ;
//      [32768,40960) WpT_tx[j*128+c] ; [40960,45056) WpT_us[j*64+c] ;
//      [45056,53248) W2T[m*256+k]
__global__ __launch_bounds__(256) void prep_transpose(const float* __restrict__ W1a,
    const float* __restrict__ W1b, const float* __restrict__ Wpt,
    const float* __restrict__ Wpu, const float* __restrict__ W2, float* __restrict__ out)
{
    int i = blockIdx.x * 256 + threadIdx.x;
    if (i < 16384) {
        int hj = i >> 6, c = i & 63;
        out[i] = W1a[c * 256 + hj];
    } else if (i < 32768) {
        int k = i - 16384; int hj = k >> 6, c = k & 63;
        out[i] = W1b[c * 256 + hj];
    } else if (i < 40960) {
        int k = i - 32768; int j = k >> 7, c = k & 127;
        out[i] = Wpt[c * 64 + j];
    } else if (i < 45056) {
        int k = i - 40960; int j = k >> 6, c = k & 63;
        out[i] = Wpu[c * 64 + j];
    } else if (i < 53248) {
        int k = i - 45056; int m = k >> 8, kk = k & 255;
        out[i] = W2[kk * 32 + m];
    }
}

// ================= fused projection + attention dots (K = 128) =================
// wave -> 8 consecutive nodes; lane = output col j. W column in 32 named float4s.
__global__ __launch_bounds__(256, 3) void proj_attn_128(
    const float* __restrict__ X, const float* __restrict__ WT, const float* __restrict__ bias,
    const float* __restrict__ Ma, const float* __restrict__ Mb,
    float* __restrict__ H, float* __restrict__ oa, float* __restrict__ ob, int Nw)
{
    const int lane = threadIdx.x & 63;
    const int gw = blockIdx.x * 4 + (threadIdx.x >> 6);
    if (gw >= Nw) return;
    const float4* Wc = (const float4*)(WT + (size_t)lane * 128);
    WDECL32;
    const float breg = bias[lane];
    const float ma0 = Ma[lane * 4], ma1 = Ma[lane * 4 + 1], ma2 = Ma[lane * 4 + 2], ma3 = Ma[lane * 4 + 3];
    const float mb0 = Mb[lane * 4], mb1 = Mb[lane * 4 + 1], mb2 = Mb[lane * 4 + 2], mb3 = Mb[lane * 4 + 3];
    const int n0 = gw * 8;
    for (int nn = 0; nn < 8; ++nn) {
        const int n = n0 + nn;
        const float4* xr = (const float4*)(X + (size_t)n * 128);
        float a0 = breg, a1 = 0.f, a2 = 0.f, a3 = 0.f;
        F32(xr);
        float v = (a0 + a1) + (a2 + a3);
        v = v > 0.f ? v : (expf(v) - 1.f);
        H[(size_t)n * 64 + lane] = v;
        reduce8_store(v * ma0, v * ma1, v * ma2, v * ma3, v * mb0, v * mb1, v * mb2, v * mb3,
                      lane, oa + (size_t)n * 4, ob + (size_t)n * 4);
    }
}

// ================= fused projection + attention dots (K = 64) =================
__global__ __launch_bounds__(256, 4) void proj_attn_64(
    const float* __restrict__ X, const float* __restrict__ WT, const float* __restrict__ bias,
    const float* __restrict__ Ma, const float* __restrict__ Mb,
    float* __restrict__ H, float* __restrict__ oa, float* __restrict__ ob, int Nw)
{
    const int lane = threadIdx.x & 63;
    const int gw = blockIdx.x * 4 + (threadIdx.x >> 6);
    if (gw >= Nw) return;
    const float4* Wc = (const float4*)(WT + (size_t)lane * 64);
    WDECL16;
    const float breg = bias[lane];
    const float ma0 = Ma[lane * 4], ma1 = Ma[lane * 4 + 1], ma2 = Ma[lane * 4 + 2], ma3 = Ma[lane * 4 + 3];
    const float mb0 = Mb[lane * 4], mb1 = Mb[lane * 4 + 1], mb2 = Mb[lane * 4 + 2], mb3 = Mb[lane * 4 + 3];
    const int n0 = gw * 8;
    for (int nn = 0; nn < 8; ++nn) {
        const int n = n0 + nn;
        const float4* xr = (const float4*)(X + (size_t)n * 64);
        float a0 = breg, a1 = 0.f, a2 = 0.f, a3 = 0.f;
        F16(xr);
        float v = (a0 + a1) + (a2 + a3);
        v = v > 0.f ? v : (expf(v) - 1.f);
        H[(size_t)n * 64 + lane] = v;
        reduce8_store(v * ma0, v * ma1, v * ma2, v * ma3, v * mb0, v * mb1, v * mb2, v * mb3,
                      lane, oa + (size_t)n * 4, ob + (size_t)n * 4);
    }
}

// ================= merged CSR build (both edge types per launch) =================
__global__ __launch_bounds__(256) void hist2_kernel(const int* __restrict__ dst_t,
    const int* __restrict__ dst_u, int* __restrict__ deg_t, int* __restrict__ deg_u)
{
    int e = blockIdx.x * 256 + threadIdx.x;
    if (e < NE) atomicAdd(&deg_t[dst_t[e]], 1);
    else {
        e -= NE;
        if (e < NE) atomicAdd(&deg_u[dst_u[e]], 1);
    }
}

__global__ __launch_bounds__(256) void block_sum2_kernel(const int* __restrict__ deg_t,
    int* __restrict__ bsum_t, const int* __restrict__ deg_u, int* __restrict__ bsum_u)
{
    __shared__ int lds[256];
    int b = blockIdx.x, t = threadIdx.x;
    const int* deg; int* bsum; int Nd, lb;
    if (b < NB_T) { deg = deg_t; bsum = bsum_t; Nd = N_TX; lb = b; }
    else         { deg = deg_u; bsum = bsum_u; Nd = N_USER; lb = b - NB_T; }
    int i = lb * 256 + t;
    lds[t] = (i < Nd) ? deg[i] : 0;
    __syncthreads();
    for (int o = 128; o > 0; o >>= 1) {
        if (t < o) lds[t] += lds[t + o];
        __syncthreads();
    }
    if (t == 0) bsum[lb] = lds[0];
}

__global__ __launch_bounds__(512) void scan_bsum2_kernel(int* __restrict__ bt,
    int* __restrict__ bu)
{
    __shared__ int lds[512];
    int t = threadIdx.x;
    {
        int v = (t < NB_T) ? bt[t] : 0;
        lds[t] = v;
        __syncthreads();
        for (int o = 1; o < 512; o <<= 1) {
            int x = (t >= o) ? lds[t - o] : 0;
            __syncthreads();
            lds[t] += x;
            __syncthreads();
        }
        if (t < NB_T) bt[t] = lds[t] - v;
        __syncthreads();
    }
    {
        int v = (t < NB_U) ? bu[t] : 0;
        lds[t] = v;
        __syncthreads();
        for (int o = 1; o < 512; o <<= 1) {
            int x = (t >= o) ? lds[t - o] : 0;
            __syncthreads();
            lds[t] += x;
            __syncthreads();
        }
        if (t < NB_U) bu[t] = lds[t] - v;
    }
}

__global__ __launch_bounds__(256) void scan_final2_kernel(
    const int* __restrict__ deg_t, const int* __restrict__ be_t,
    int* __restrict__ rowptr_t, int* __restrict__ cur_t,
    const int* __restrict__ deg_u, const int* __restrict__ be_u,
    int* __restrict__ rowptr_u, int* __restrict__ cur_u)
{
    __shared__ int lds[256];
    int b = blockIdx.x, t = threadIdx.x;
    const int* deg; const int* be; int* rowptr; int* cursor; int Nd, lb;
    if (b < NB_T) { deg = deg_t; be = be_t; rowptr = rowptr_t; cursor = cur_t; Nd = N_TX; lb = b; }
    else         { deg = deg_u; be = be_u; rowptr = rowptr_u; cursor = cur_u; Nd = N_USER; lb = b - NB_T; }
    int i = lb * 256 + t;
    int v = (i < Nd) ? deg[i] : 0;
    lds[t] = v;
    __syncthreads();
    for (int o = 1; o < 256; o <<= 1) {
        int x = (t >= o) ? lds[t - o] : 0;
        __syncthreads();
        lds[t] += x;
        __syncthreads();
    }
    int excl = lds[t] - v + be[lb];
    if (i < Nd) {
        rowptr[i] = excl;
        cursor[i] = excl;
        if (i == Nd - 1) rowptr[Nd] = NE;
    }
}

__global__ __launch_bounds__(256) void scatter2_kernel(
    const int* __restrict__ src_t, const int* __restrict__ dst_t,
    int* __restrict__ cur_t, int* __restrict__ csr_t,
    const int* __restrict__ src_u, const int* __restrict__ dst_u,
    int* __restrict__ cur_u, int* __restrict__ csr_u)
{
    int e = blockIdx.x * 256 + threadIdx.x;
    if (e < NE) {
        int p = atomicAdd(&cur_t[dst_t[e]], 1);
        csr_t[p] = src_t[e];
    } else {
        e -= NE;
        if (e < NE) {
            int p = atomicAdd(&cur_u[dst_u[e]], 1);
            csr_u[p] = src_u[e];
        }
    }
}

// ================= conv1 aggregation: one wave per dst node =================
__device__ __forceinline__ void acc_edge(int s, int lane,
    const float* __restrict__ als, const float* __restrict__ hsrc, const float4& A,
    float& a0, float& a1, float& a2, float& a3,
    float& w0, float& w1, float& w2, float& w3)
{
    float4 v = *(const float4*)(als + (size_t)s * 4);
    float x = hsrc[(size_t)s * 64 + lane];
    float e0 = lrelu_exp(v.x + A.x);
    float e1 = lrelu_exp(v.y + A.y);
    float e2 = lrelu_exp(v.z + A.z);
    float e3 = lrelu_exp(v.w + A.w);
    a0 = fmaf(e0, x, a0); w0 += e0;
    a1 = fmaf(e1, x, a1); w1 += e1;
    a2 = fmaf(e2, x, a2); w2 += e2;
    a3 = fmaf(e3, x, a3); w3 += e3;
}

__global__ __launch_bounds__(256) void agg_conv1_kernel(const int* __restrict__ rowptr,
    const int* __restrict__ csr, const float* __restrict__ hsrc,
    const float* __restrict__ als, const float* __restrict__ ald,
    float* __restrict__ agg, int Nd)
{
    int d = blockIdx.x * 4 + (threadIdx.x >> 6);
    int lane = threadIdx.x & 63;
    if (d >= Nd) return;
    int beg = rowptr[d], end = rowptr[d + 1];
    float4 A = *(const float4*)(ald + (size_t)d * 4);
    float a0 = 0.f, a1 = 0.f, a2 = 0.f, a3 = 0.f;
    float w0 = 0.f, w1 = 0.f, w2 = 0.f, w3 = 0.f;
    int i = beg;
    for (; i + 2 <= end; i += 2) {
        acc_edge(csr[i],     lane, als, hsrc, A, a0, a1, a2, a3, w0, w1, w2, w3);
        acc_edge(csr[i + 1], lane, als, hsrc, A, a0, a1, a2, a3, w0, w1, w2, w3);
    }
    if (i < end)
        acc_edge(csr[i], lane, als, hsrc, A, a0, a1, a2, a3, w0, w1, w2, w3);
    float* o = agg + (size_t)d * 256;
    o[lane]       = a0 / (w0 + 1e-16f);
    o[64 + lane]  = a1 / (w1 + 1e-16f);
    o[128 + lane] = a2 / (w2 + 1e-16f);
    o[192 + lane] = a3 / (w3 + 1e-16f);
}

// ================= conv1 u2t transform v4: named-reg W, broadcast x, no LDS ============
// block = 32 nodes x 4 head-waves; dot_part[h*Nd + n] = elu(t1_row_h) . vvec_h
__global__ __launch_bounds__(256, 4) void transform_u2t_v4(
    const float* __restrict__ agg, const float* __restrict__ W1T,
    const float* __restrict__ b1, const float* __restrict__ vvec,
    float* __restrict__ dot_part, int Nd)
{
    const int lane = threadIdx.x & 63;
    const int w = threadIdx.x >> 6;
    const int base = blockIdx.x * 32;
    const float4* Wc = (const float4*)(W1T + (size_t)(w * 64 + lane) * 64);
    WDECL16;
    const float breg = b1[w * 64 + lane];
    const float vreg = vvec[w * 64 + lane];
    float* dp = dot_part + (size_t)w * Nd;
    for (int nn = 0; nn < 32; ++nn) {
        const int gn = base + nn;
        const float4* xr = (const float4*)(agg + (size_t)gn * 256 + w * 64);
        float a0 = breg, a1 = 0.f, a2 = 0.f, a3 = 0.f;
        F16(xr);
        float v = (a0 + a1) + (a2 + a3);
        v = v > 0.f ? v : (expf(v) - 1.f);
        float s = wave_sum(v * vreg);
        if (lane == 0) dp[gn] = s;
    }
}

// ================= conv1 t2u transform v4 + fused conv2 projection ============
// phase 1: u1 slice per head into padded LDS tile + als2 partials (u1 never hits HBM)
// phase 2: hs2[n, :32] = u1_row @ W2 straight from LDS
__global__ __launch_bounds__(256, 4) void transform_t2u_v4(
    const float* __restrict__ agg, const float* __restrict__ W1T,
    const float* __restrict__ b1, const float* __restrict__ vvec,
    const float* __restrict__ W2T, float* __restrict__ dot_part,
    float* __restrict__ hs2, int Nd)
{
    __shared__ float sU[32 * 260];      // 33,280 B; stride 260 kills phase-2 bank conflicts
    const int lane = threadIdx.x & 63;
    const int w = threadIdx.x >> 6;
    const int base = blockIdx.x * 32;
    {
        const float4* Wc = (const float4*)(W1T + (size_t)(w * 64 + lane) * 64);
        WDECL16;
        const float breg = b1[w * 64 + lane];
        const float vreg = vvec[w * 64 + lane];
        float* dp = dot_part + (size_t)w * Nd;
        for (int nn = 0; nn < 32; ++nn) {
            const int gn = base + nn;
            const int gi = gn < Nd ? gn : (Nd - 1);
            const float4* xr = (const float4*)(agg + (size_t)gi * 256 + w * 64);
            float a0 = breg, a1 = 0.f, a2 = 0.f, a3 = 0.f;
            F16(xr);
            float v = (a0 + a1) + (a2 + a3);
            v = v > 0.f ? v : (expf(v) - 1.f);
            sU[nn * 260 + w * 64 + lane] = v;
            float s = wave_sum(v * vreg);
            if (lane == 0 && gn < Nd) dp[gn] = s;
        }
    }
    __syncthreads();
    // phase 2: thread -> (node nl = tid>>3, col-quad mg = tid&7)
    const int nl = threadIdx.x >> 3;
    const int mg = threadIdx.x & 7;
    const float* urow = sU + nl * 260;
    const float* w2a = W2T + (size_t)(mg * 4 + 0) * 256;
    const float* w2b = W2T + (size_t)(mg * 4 + 1) * 256;
    const float* w2c = W2T + (size_t)(mg * 4 + 2) * 256;
    const float* w2d = W2T + (size_t)(mg * 4 + 3) * 256;
    float q0 = 0.f, q1 = 0.f, q2 = 0.f, q3 = 0.f;
    #pragma unroll 4
    for (int kc = 0; kc < 64; ++kc) {
        float4 u  = *(const float4*)(urow + kc * 4);
        float4 wa = *(const float4*)(w2a + kc * 4);
        float4 wb = *(const float4*)(w2b + kc * 4);
        float4 wc4 = *(const float4*)(w2c + kc * 4);
        float4 wd = *(const float4*)(w2d + kc * 4);
        q0 = fmaf(u.x, wa.x, q0); q0 = fmaf(u.y, wa.y, q0); q0 = fmaf(u.z, wa.z, q0); q0 = fmaf(u.w, wa.w, q0);
        q1 = fmaf(u.x, wb.x, q1); q1 = fmaf(u.y, wb.y, q1); q1 = fmaf(u.z, wb.z, q1); q1 = fmaf(u.w, wb.w, q1);
        q2 = fmaf(u.x, wc4.x, q2); q2 = fmaf(u.y, wc4.y, q2); q2 = fmaf(u.z, wc4.z, q2); q2 = fmaf(u.w, wc4.w, q2);
        q3 = fmaf(u.x, wd.x, q3); q3 = fmaf(u.y, wd.y, q3); q3 = fmaf(u.z, wd.z, q3); q3 = fmaf(u.w, wd.w, q3);
    }
    const int g = base + nl;
    if (g < Nd)
        *(float4*)(hs2 + (size_t)g * 32 + mg * 4) = make_float4(q0, q1, q2, q3);
}

// ------------- sum 4 head partials -------------
__global__ __launch_bounds__(256) void combine_parts(
    const float* __restrict__ ap, float* __restrict__ o1, int N1,
    const float* __restrict__ bp, float* __restrict__ o2, int N2)
{
    int i = blockIdx.x * 256 + threadIdx.x;
    if (i < N1) {
        o1[i] = ap[i] + ap[N1 + i] + ap[2 * N1 + i] + ap[3 * N1 + i];
    } else {
        int j = i - N1;
        if (j < N2)
            o2[j] = bp[j] + bp[N2 + j] + bp[2 * N2 + j] + bp[3 * N2 + j];
    }
}

// ================= conv2: fused edge-softmax + aggregation + bias/ELU + classifier ==========
__global__ __launch_bounds__(256) void conv2_fused_kernel(const int* __restrict__ rowptr,
    const int* __restrict__ csr, const float* __restrict__ hs2,
    const float* __restrict__ als2, const float* __restrict__ ald2,
    const float* __restrict__ b2, const float* __restrict__ Wc, const float* __restrict__ bc,
    float* __restrict__ out, int Nd)
{
    int d = blockIdx.x * 4 + (threadIdx.x >> 6);
    int lane = threadIdx.x & 63;
    if (d >= Nd) return;
    int beg = rowptr[d], end = rowptr[d + 1];
    float aldd = ald2[d];
    int half = lane >> 5, c = lane & 31;
    float acc = 0.f, wsum = 0.f;
    for (int i = beg + half; i < end; i += 2) {
        int s = csr[i];
        float w = lrelu_exp(als2[s] + aldd);
        acc = fmaf(w, hs2[(size_t)s * 32 + c], acc);
        wsum += w;
    }
    acc  += __shfl_down(acc, 32);
    wsum += __shfl_down(wsum, 32);
    float val = 0.f;
    if (lane < 32) {
        float t2 = acc / (wsum + 1e-16f) + b2[c];
        t2 = t2 > 0.f ? t2 : (expf(t2) - 1.f);
        val = t2 * Wc[c];
    }
    #pragma unroll
    for (int o = 16; o > 0; o >>= 1) val += __shfl_down(val, o);
    if (lane == 0) out[d] = val + bc[0];
}

extern "C" void kernel_launch(void* const* d_in, const int* in_sizes, int n_in,
                              void* d_out, int out_size, void* d_ws, size_t ws_size,
                              hipStream_t stream)
{
    const float* x_tx    = (const float*)d_in[0];
    const float* x_user  = (const float*)d_in[1];
    const int*   ei_u2t  = (const int*)d_in[2];
    const int*   ei_t2u  = (const int*)d_in[3];
    const float* Wp_tx   = (const float*)d_in[4];
    const float* bp_tx   = (const float*)d_in[5];
    const float* Wp_user = (const float*)d_in[6];
    const float* bp_user = (const float*)d_in[7];
    const float* W1_u2t  = (const float*)d_in[8];
    const float* as1_u2t = (const float*)d_in[9];
    const float* ad1_u2t = (const float*)d_in[10];
    const float* b1_u2t  = (const float*)d_in[11];
    const float* W2_u2t  = (const float*)d_in[12];
    const float* as2_u2t = (const float*)d_in[13];
    const float* ad2_u2t = (const float*)d_in[14];
    const float* b2_u2t  = (const float*)d_in[15];
    const float* W1_t2u  = (const float*)d_in[16];
    const float* as1_t2u = (const float*)d_in[17];
    const float* ad1_t2u = (const float*)d_in[18];
    const float* b1_t2u  = (const float*)d_in[19];
    const float* Wc      = (const float*)d_in[24];
    const float* bc      = (const float*)d_in[25];
    float* out = (float*)d_out;
    float* ws  = (float*)d_ws;

    const int* src_u2t = ei_u2t;            // user ids
    const int* dst_u2t = ei_u2t + NE;       // tx ids
    const int* src_t2u = ei_t2u;            // tx ids
    const int* dst_u   = ei_t2u + NE;       // user ids

    // ---- workspace layout (floats); ~39.7M floats = 158.6 MB ----
    float* h_tx   = ws;                     //  6,400,000
    float* h_us   = ws + 6400000;           //  3,200,000 (ald2p/als2p alias after it dies)
    float* hs2    = ws + 9600000;           //  1,600,000
    float* als2   = ws + 11200000;          //     50,000
    float* ald2   = ws + 11250000;          //    100,000
    float* als_us = ws + 11350000;          //    200,000
    float* ald_us = ws + 11550000;          //    200,000
    float* als_tx = ws + 11750000;          //    400,000
    float* ald_tx = ws + 12150000;          //    400,000
    float* agg    = ws + 12550000;          // 25,600,000 (u2t then t2u, sequential)
    float* avec   = ws + 38150000;          //      1,536
    float* WT     = ws + 38151552;          //     53,248 (transposed weights)
    // partials alias dead h_us (dead after agg_conv1 u2t)
    float* ald2p = h_us;                    //    400,000 (4 x N_TX)
    float* als2p = h_us + 400000;           //    200,000 (4 x N_USER)
    // ---- int region ----
    int* ibase    = (int*)(ws + 38210000);
    int* deg_t    = ibase;                  //   100,000
    int* deg_u    = ibase + 100000;         //    50,000
    int* rowptr_t = ibase + 150000;         //   100,001
    int* cur_t    = ibase + 250001;         //   100,000
    int* csr_t    = ibase + 350001;         //   500,000
    int* rowptr_u = ibase + 850001;         //    50,001
    int* cur_u    = ibase + 900002;         //    50,000
    int* csr_u    = ibase + 950002;         //   500,000
    int* bsum_t   = ibase + 1450002;        //       512
    int* bsum_u   = ibase + 1450514;        //       512

    float* Msrc_u2t = avec + 0;
    float* Mdst_u2t = avec + 256;
    float* Msrc_t2u = avec + 512;
    float* Mdst_t2u = avec + 768;
    float* vsrc2    = avec + 1024;          // fold(W2, as2)
    float* vdst2    = avec + 1280;          // fold(W2, ad2)

    float* W1T_u2t = WT;
    float* W1T_t2u = WT + 16384;
    float* WpT_tx  = WT + 32768;
    float* WpT_us  = WT + 40960;
    float* W2T     = WT + 45056;

    // ---- fold attention vectors into weights ----
    AVArgs6 av;
    av.t[0] = { W1_u2t, as1_u2t, Msrc_u2t, HID, NH, HID };
    av.t[1] = { W1_u2t, ad1_u2t, Mdst_u2t, HID, NH, HID };
    av.t[2] = { W1_t2u, as1_t2u, Msrc_t2u, HID, NH, HID };
    av.t[3] = { W1_t2u, ad1_t2u, Mdst_t2u, HID, NH, HID };
    av.t[4] = { W2_u2t, as2_u2t, vsrc2, HC1, 1, OUTC };
    av.t[5] = { W2_u2t, ad2_u2t, vdst2, HC1, 1, OUTC };
    attn_vecs_kernel<<<6, 256, 0, stream>>>(av);

    // ---- transpose weights for the reg-resident kernels ----
    prep_transpose<<<208, 256, 0, stream>>>(W1_u2t, W1_t2u, Wp_tx, Wp_user, W2_u2t, WT);

    // ---- zero degree histograms ----
    hipMemsetAsync(deg_t, 0, 150000 * sizeof(int), stream);

    // ---- CSR build (both edge types, 5 launches) ----
    hist2_kernel<<<(2 * NE + 255) / 256, 256, 0, stream>>>(dst_u2t, dst_u, deg_t, deg_u);
    block_sum2_kernel<<<NB_T + NB_U, 256, 0, stream>>>(deg_t, bsum_t, deg_u, bsum_u);
    scan_bsum2_kernel<<<1, 512, 0, stream>>>(bsum_t, bsum_u);
    scan_final2_kernel<<<NB_T + NB_U, 256, 0, stream>>>(
        deg_t, bsum_t, rowptr_t, cur_t, deg_u, bsum_u, rowptr_u, cur_u);
    scatter2_kernel<<<(2 * NE + 255) / 256, 256, 0, stream>>>(
        src_u2t, dst_u2t, cur_t, csr_t, src_t2u, dst_u, cur_u, csr_u);

    // ---- fused projection + attention dots ----
    proj_attn_128<<<3125, 256, 0, stream>>>(
        x_tx, WpT_tx, bp_tx, Mdst_u2t, Msrc_t2u, h_tx, ald_tx, als_tx, N_TX / 8);
    proj_attn_64<<<1563, 256, 0, stream>>>(
        x_user, WpT_us, bp_user, Msrc_u2t, Mdst_t2u, h_us, als_us, ald_us, N_USER / 8);

    // ================= conv1, u2t (dst = tx) =================
    agg_conv1_kernel<<<(N_TX + 3) / 4, 256, 0, stream>>>(
        rowptr_t, csr_t, h_us, als_us, ald_tx, agg, N_TX);
    transform_u2t_v4<<<N_TX / 32, 256, 0, stream>>>(
        agg, W1T_u2t, b1_u2t, vdst2, ald2p, N_TX);

    // ================= conv1, t2u (dst = user) + fused conv2 projection ==========
    agg_conv1_kernel<<<(N_USER + 3) / 4, 256, 0, stream>>>(
        rowptr_u, csr_u, h_tx, als_tx, ald_us, agg, N_USER);
    transform_t2u_v4<<<(N_USER + 31) / 32, 256, 0, stream>>>(
        agg, W1T_t2u, b1_t2u, vsrc2, W2T, als2p, hs2, N_USER);

    // ---- combine head partials ----
    combine_parts<<<(N_TX + N_USER + 255) / 256, 256, 0, stream>>>(
        ald2p, ald2, N_TX, als2p, als2, N_USER);

    // ================= conv2 + classifier =================
    conv2_fused_kernel<<<(N_TX + 3) / 4, 256, 0, stream>>>(
        rowptr_t, csr_t, hs2, als2, ald2, b2_u2t, Wc, bc, out, N_TX);
}

// Round 9
// 1261.693 us; speedup vs baseline: 1.3775x; 1.3775x over previous
//
#include <hip/hip_runtime.h>
#include <hip/hip_bf16.h>
#include <math.h>

#define N_TX   100000
#define N_USER 50000
#define F_TX   128
#define F_USER 64
#define HID    64
#define NH     4
#define OUTC   32
#define NE     500000
#define HC1    256          // NH*HID
#define SLOPE  0.2f
#define NB_T   391          // (N_TX+255)/256
#define NB_U   196          // (N_USER+255)/256

__device__ __forceinline__ float elu_f(float x) { return x > 0.f ? x : (expf(x) - 1.f); }
__device__ __forceinline__ float lrelu_exp(float x) { x = x > 0.f ? x : SLOPE * x; return expf(x); }

// full-wave sum via xor butterfly (all lanes end with the total)
__device__ __forceinline__ float wave_sum(float s)
{
    s += __shfl_xor(s, 32); s += __shfl_xor(s, 16); s += __shfl_xor(s, 8);
    s += __shfl_xor(s, 4);  s += __shfl_xor(s, 2);  s += __shfl_xor(s, 1);
    return s;
}

// ---- named-register W tile: 16 float4 = 64 VGPRs (fits under launch_bounds(256,4) cap) ----
#define WDECL16 \
    const float4 WW0=Wc[0],WW1=Wc[1],WW2=Wc[2],WW3=Wc[3],WW4=Wc[4],WW5=Wc[5],WW6=Wc[6],WW7=Wc[7], \
                 WW8=Wc[8],WW9=Wc[9],WW10=Wc[10],WW11=Wc[11],WW12=Wc[12],WW13=Wc[13],WW14=Wc[14],WW15=Wc[15];
#define FS(i, xr) { const float4 x_ = (xr)[i]; \
    a0 = fmaf(x_.x, WW##i.x, a0); a1 = fmaf(x_.y, WW##i.y, a1); \
    a2 = fmaf(x_.z, WW##i.z, a2); a3 = fmaf(x_.w, WW##i.w, a3); }
#define F16(xr) FS(0,xr) FS(1,xr) FS(2,xr) FS(3,xr) FS(4,xr) FS(5,xr) FS(6,xr) FS(7,xr) \
                FS(8,xr) FS(9,xr) FS(10,xr) FS(11,xr) FS(12,xr) FS(13,xr) FS(14,xr) FS(15,xr)

// ---------------- tiled fp32 GEMM: C = act(A[N,K] @ B[K,M] + bias) ----------------
__global__ __launch_bounds__(256) void gemm_kernel(const float* __restrict__ A,
    const float* __restrict__ B, const float* __restrict__ bias,
    float* __restrict__ C, int N, int K, int M, int act)
{
    __shared__ float As[16][65];
    __shared__ float Bs[16][65];
    const int tid = threadIdx.x;
    const int tx = tid % 16, ty = tid / 16;
    const int row0 = blockIdx.y * 64, col0 = blockIdx.x * 64;
    float acc[4][4] = {};
    for (int k0 = 0; k0 < K; k0 += 16) {
        #pragma unroll
        for (int i = 0; i < 4; ++i) {
            int idx = tid * 4 + i;           // 64x16 A tile
            int r = idx >> 4, kk = idx & 15;
            int gr = row0 + r;
            As[kk][r] = (gr < N) ? A[(size_t)gr * K + (k0 + kk)] : 0.f;
        }
        #pragma unroll
        for (int i = 0; i < 4; ++i) {
            int idx = tid * 4 + i;           // 16x64 B tile
            int kk = idx >> 6, c = idx & 63;
            int gc = col0 + c;
            Bs[kk][c] = (gc < M) ? B[(size_t)(k0 + kk) * M + gc] : 0.f;
        }
        __syncthreads();
        #pragma unroll
        for (int kk = 0; kk < 16; ++kk) {
            float a4[4], b4[4];
            #pragma unroll
            for (int i = 0; i < 4; ++i) a4[i] = As[kk][ty * 4 + i];
            #pragma unroll
            for (int j = 0; j < 4; ++j) b4[j] = Bs[kk][tx * 4 + j];
            #pragma unroll
            for (int i = 0; i < 4; ++i)
                #pragma unroll
                for (int j = 0; j < 4; ++j) acc[i][j] += a4[i] * b4[j];
        }
        __syncthreads();
    }
    #pragma unroll
    for (int i = 0; i < 4; ++i) {
        int r = row0 + ty * 4 + i;
        if (r >= N) continue;
        #pragma unroll
        for (int j = 0; j < 4; ++j) {
            int c = col0 + tx * 4 + j;
            if (c >= M) continue;
            float v = acc[i][j] + (bias ? bias[c] : 0.f);
            if (act == 1) v = elu_f(v);
            C[(size_t)r * M + c] = v;
        }
    }
}

// ------------- fold attention vectors into weights: Mv[k,h] = sum_c W[k,h*C+c]*a[h,c] -------------
struct AVArgs  { const float* W; const float* a; float* out; int K; int H; int C; };
struct AVArgs6 { AVArgs t[6]; };

__global__ void attn_vecs_kernel(AVArgs6 args)
{
    AVArgs A = args.t[blockIdx.x];
    int tid = threadIdx.x;
    if (tid < A.K * A.H) {
        int k = tid % A.K, h = tid / A.K;
        float s = 0.f;
        const float* wrow = A.W + (size_t)k * (A.H * A.C) + h * A.C;
        const float* arow = A.a + h * A.C;
        for (int c = 0; c < A.C; ++c) s += wrow[c] * arow[c];
        A.out[k * A.H + h] = s;
    }
}

// ------------- transpose weights into column-contiguous layouts -------------
// out: [0,16384) W1T_u2t[(h*64+j)*64+c] ; [16384,32768) W1T_t2u ; [32768,40960) W2T[m*256+k]
__global__ __launch_bounds__(256) void prep_transpose(const float* __restrict__ W1a,
    const float* __restrict__ W1b, const float* __restrict__ W2, float* __restrict__ out)
{
    int i = blockIdx.x * 256 + threadIdx.x;
    if (i < 16384) {
        int hj = i >> 6, c = i & 63;
        out[i] = W1a[c * 256 + hj];
    } else if (i < 32768) {
        int k = i - 16384; int hj = k >> 6, c = k & 63;
        out[i] = W1b[c * 256 + hj];
    } else if (i < 40960) {
        int k = i - 32768; int m = k >> 8, kk = k & 255;
        out[i] = W2[kk * 32 + m];
    }
}

// ------------- per-node attention scalars for BOTH node types in one launch -------------
__global__ __launch_bounds__(256) void node_attn8_dual(
    const float* __restrict__ Xt, const float* __restrict__ Mta, const float* __restrict__ Mtb,
    float* __restrict__ ota, float* __restrict__ otb,
    const float* __restrict__ Xu, const float* __restrict__ Mua, const float* __restrict__ Mub,
    float* __restrict__ oua, float* __restrict__ oub)
{
    int wave = blockIdx.x * 4 + (threadIdx.x >> 6);
    int lane = threadIdx.x & 63;
    const float* X; const float* Ma; const float* Mb; float* oa; float* ob;
    if (wave < N_TX) {              // N_TX % 4 == 0 -> wave-uniform branch per block
        X = Xt + (size_t)wave * 64; Ma = Mta; Mb = Mtb;
        oa = ota + (size_t)wave * 4; ob = otb + (size_t)wave * 4;
    } else {
        int n = wave - N_TX;
        if (n >= N_USER) return;
        X = Xu + (size_t)n * 64; Ma = Mua; Mb = Mub;
        oa = oua + (size_t)n * 4; ob = oub + (size_t)n * 4;
    }
    float x = X[lane];
    float a0 = x * Ma[lane * 4 + 0];
    float a1 = x * Ma[lane * 4 + 1];
    float a2 = x * Ma[lane * 4 + 2];
    float a3 = x * Ma[lane * 4 + 3];
    float b0 = x * Mb[lane * 4 + 0];
    float b1 = x * Mb[lane * 4 + 1];
    float b2 = x * Mb[lane * 4 + 2];
    float b3 = x * Mb[lane * 4 + 3];
    for (int off = 32; off > 0; off >>= 1) {
        a0 += __shfl_down(a0, off); a1 += __shfl_down(a1, off);
        a2 += __shfl_down(a2, off); a3 += __shfl_down(a3, off);
        b0 += __shfl_down(b0, off); b1 += __shfl_down(b1, off);
        b2 += __shfl_down(b2, off); b3 += __shfl_down(b3, off);
    }
    if (lane == 0) {
        oa[0] = a0; oa[1] = a1; oa[2] = a2; oa[3] = a3;
        ob[0] = b0; ob[1] = b1; ob[2] = b2; ob[3] = b3;
    }
}

// ================= merged CSR build (both edge types per launch) =================
__global__ __launch_bounds__(256) void hist2_kernel(const int* __restrict__ dst_t,
    const int* __restrict__ dst_u, int* __restrict__ deg_t, int* __restrict__ deg_u)
{
    int e = blockIdx.x * 256 + threadIdx.x;
    if (e < NE) atomicAdd(&deg_t[dst_t[e]], 1);
    else {
        e -= NE;
        if (e < NE) atomicAdd(&deg_u[dst_u[e]], 1);
    }
}

__global__ __launch_bounds__(256) void block_sum2_kernel(const int* __restrict__ deg_t,
    int* __restrict__ bsum_t, const int* __restrict__ deg_u, int* __restrict__ bsum_u)
{
    __shared__ int lds[256];
    int b = blockIdx.x, t = threadIdx.x;
    const int* deg; int* bsum; int Nd, lb;
    if (b < NB_T) { deg = deg_t; bsum = bsum_t; Nd = N_TX; lb = b; }
    else         { deg = deg_u; bsum = bsum_u; Nd = N_USER; lb = b - NB_T; }
    int i = lb * 256 + t;
    lds[t] = (i < Nd) ? deg[i] : 0;
    __syncthreads();
    for (int o = 128; o > 0; o >>= 1) {
        if (t < o) lds[t] += lds[t + o];
        __syncthreads();
    }
    if (t == 0) bsum[lb] = lds[0];
}

__global__ __launch_bounds__(512) void scan_bsum2_kernel(int* __restrict__ bt,
    int* __restrict__ bu)
{
    __shared__ int lds[512];
    int t = threadIdx.x;
    {
        int v = (t < NB_T) ? bt[t] : 0;
        lds[t] = v;
        __syncthreads();
        for (int o = 1; o < 512; o <<= 1) {
            int x = (t >= o) ? lds[t - o] : 0;
            __syncthreads();
            lds[t] += x;
            __syncthreads();
        }
        if (t < NB_T) bt[t] = lds[t] - v;
        __syncthreads();
    }
    {
        int v = (t < NB_U) ? bu[t] : 0;
        lds[t] = v;
        __syncthreads();
        for (int o = 1; o < 512; o <<= 1) {
            int x = (t >= o) ? lds[t - o] : 0;
            __syncthreads();
            lds[t] += x;
            __syncthreads();
        }
        if (t < NB_U) bu[t] = lds[t] - v;
    }
}

__global__ __launch_bounds__(256) void scan_final2_kernel(
    const int* __restrict__ deg_t, const int* __restrict__ be_t,
    int* __restrict__ rowptr_t, int* __restrict__ cur_t,
    const int* __restrict__ deg_u, const int* __restrict__ be_u,
    int* __restrict__ rowptr_u, int* __restrict__ cur_u)
{
    __shared__ int lds[256];
    int b = blockIdx.x, t = threadIdx.x;
    const int* deg; const int* be; int* rowptr; int* cursor; int Nd, lb;
    if (b < NB_T) { deg = deg_t; be = be_t; rowptr = rowptr_t; cursor = cur_t; Nd = N_TX; lb = b; }
    else         { deg = deg_u; be = be_u; rowptr = rowptr_u; cursor = cur_u; Nd = N_USER; lb = b - NB_T; }
    int i = lb * 256 + t;
    int v = (i < Nd) ? deg[i] : 0;
    lds[t] = v;
    __syncthreads();
    for (int o = 1; o < 256; o <<= 1) {
        int x = (t >= o) ? lds[t - o] : 0;
        __syncthreads();
        lds[t] += x;
        __syncthreads();
    }
    int excl = lds[t] - v + be[lb];
    if (i < Nd) {
        rowptr[i] = excl;
        cursor[i] = excl;
        if (i == Nd - 1) rowptr[Nd] = NE;
    }
}

__global__ __launch_bounds__(256) void scatter2_kernel(
    const int* __restrict__ src_t, const int* __restrict__ dst_t,
    int* __restrict__ cur_t, int* __restrict__ csr_t,
    const int* __restrict__ src_u, const int* __restrict__ dst_u,
    int* __restrict__ cur_u, int* __restrict__ csr_u)
{
    int e = blockIdx.x * 256 + threadIdx.x;
    if (e < NE) {
        int p = atomicAdd(&cur_t[dst_t[e]], 1);
        csr_t[p] = src_t[e];
    } else {
        e -= NE;
        if (e < NE) {
            int p = atomicAdd(&cur_u[dst_u[e]], 1);
            csr_u[p] = src_u[e];
        }
    }
}

// ================= conv1 aggregation: one wave per dst node =================
__device__ __forceinline__ void acc_edge(int s, int lane,
    const float* __restrict__ als, const float* __restrict__ hsrc, const float4& A,
    float& a0, float& a1, float& a2, float& a3,
    float& w0, float& w1, float& w2, float& w3)
{
    float4 v = *(const float4*)(als + (size_t)s * 4);
    float x = hsrc[(size_t)s * 64 + lane];
    float e0 = lrelu_exp(v.x + A.x);
    float e1 = lrelu_exp(v.y + A.y);
    float e2 = lrelu_exp(v.z + A.z);
    float e3 = lrelu_exp(v.w + A.w);
    a0 = fmaf(e0, x, a0); w0 += e0;
    a1 = fmaf(e1, x, a1); w1 += e1;
    a2 = fmaf(e2, x, a2); w2 += e2;
    a3 = fmaf(e3, x, a3); w3 += e3;
}

__global__ __launch_bounds__(256) void agg_conv1_kernel(const int* __restrict__ rowptr,
    const int* __restrict__ csr, const float* __restrict__ hsrc,
    const float* __restrict__ als, const float* __restrict__ ald,
    float* __restrict__ agg, int Nd)
{
    int d = blockIdx.x * 4 + (threadIdx.x >> 6);
    int lane = threadIdx.x & 63;
    if (d >= Nd) return;
    int beg = rowptr[d], end = rowptr[d + 1];
    float4 A = *(const float4*)(ald + (size_t)d * 4);
    float a0 = 0.f, a1 = 0.f, a2 = 0.f, a3 = 0.f;
    float w0 = 0.f, w1 = 0.f, w2 = 0.f, w3 = 0.f;
    int i = beg;
    for (; i + 2 <= end; i += 2) {
        acc_edge(csr[i],     lane, als, hsrc, A, a0, a1, a2, a3, w0, w1, w2, w3);
        acc_edge(csr[i + 1], lane, als, hsrc, A, a0, a1, a2, a3, w0, w1, w2, w3);
    }
    if (i < end)
        acc_edge(csr[i], lane, als, hsrc, A, a0, a1, a2, a3, w0, w1, w2, w3);
    float* o = agg + (size_t)d * 256;
    o[lane]       = a0 / (w0 + 1e-16f);
    o[64 + lane]  = a1 / (w1 + 1e-16f);
    o[128 + lane] = a2 / (w2 + 1e-16f);
    o[192 + lane] = a3 / (w3 + 1e-16f);
}

// ================= conv1 u2t transform v4: named-reg W, broadcast x, no LDS ============
// block = 32 nodes x 4 head-waves; dot_part[h*Nd + n] = elu(t1_row_h) . vvec_h
__global__ __launch_bounds__(256, 4) void transform_u2t_v4(
    const float* __restrict__ agg, const float* __restrict__ W1T,
    const float* __restrict__ b1, const float* __restrict__ vvec,
    float* __restrict__ dot_part, int Nd)
{
    const int lane = threadIdx.x & 63;
    const int w = threadIdx.x >> 6;
    const int base = blockIdx.x * 32;
    const float4* Wc = (const float4*)(W1T + (size_t)(w * 64 + lane) * 64);
    WDECL16;
    const float breg = b1[w * 64 + lane];
    const float vreg = vvec[w * 64 + lane];
    float* dp = dot_part + (size_t)w * Nd;
    for (int nn = 0; nn < 32; ++nn) {
        const int gn = base + nn;
        const float4* xr = (const float4*)(agg + (size_t)gn * 256 + w * 64);
        float a0 = breg, a1 = 0.f, a2 = 0.f, a3 = 0.f;
        F16(xr);
        float v = (a0 + a1) + (a2 + a3);
        v = v > 0.f ? v : (expf(v) - 1.f);
        float s = wave_sum(v * vreg);
        if (lane == 0) dp[gn] = s;
    }
}

// ================= conv1 t2u transform v4 + fused conv2 projection ============
__global__ __launch_bounds__(256, 4) void transform_t2u_v4(
    const float* __restrict__ agg, const float* __restrict__ W1T,
    const float* __restrict__ b1, const float* __restrict__ vvec,
    const float* __restrict__ W2T, float* __restrict__ dot_part,
    float* __restrict__ hs2, int Nd)
{
    __shared__ float sU[32 * 260];      // 33,280 B; stride 260 kills phase-2 bank conflicts
    const int lane = threadIdx.x & 63;
    const int w = threadIdx.x >> 6;
    const int base = blockIdx.x * 32;
    {
        const float4* Wc = (const float4*)(W1T + (size_t)(w * 64 + lane) * 64);
        WDECL16;
        const float breg = b1[w * 64 + lane];
        const float vreg = vvec[w * 64 + lane];
        float* dp = dot_part + (size_t)w * Nd;
        for (int nn = 0; nn < 32; ++nn) {
            const int gn = base + nn;
            const int gi = gn < Nd ? gn : (Nd - 1);
            const float4* xr = (const float4*)(agg + (size_t)gi * 256 + w * 64);
            float a0 = breg, a1 = 0.f, a2 = 0.f, a3 = 0.f;
            F16(xr);
            float v = (a0 + a1) + (a2 + a3);
            v = v > 0.f ? v : (expf(v) - 1.f);
            sU[nn * 260 + w * 64 + lane] = v;
            float s = wave_sum(v * vreg);
            if (lane == 0 && gn < Nd) dp[gn] = s;
        }
    }
    __syncthreads();
    // phase 2: thread -> (node nl = tid>>3, col-quad mg = tid&7)
    const int nl = threadIdx.x >> 3;
    const int mg = threadIdx.x & 7;
    const float* urow = sU + nl * 260;
    const float* w2a = W2T + (size_t)(mg * 4 + 0) * 256;
    const float* w2b = W2T + (size_t)(mg * 4 + 1) * 256;
    const float* w2c = W2T + (size_t)(mg * 4 + 2) * 256;
    const float* w2d = W2T + (size_t)(mg * 4 + 3) * 256;
    float q0 = 0.f, q1 = 0.f, q2 = 0.f, q3 = 0.f;
    #pragma unroll 4
    for (int kc = 0; kc < 64; ++kc) {
        float4 u  = *(const float4*)(urow + kc * 4);
        float4 wa = *(const float4*)(w2a + kc * 4);
        float4 wb = *(const float4*)(w2b + kc * 4);
        float4 wc4 = *(const float4*)(w2c + kc * 4);
        float4 wd = *(const float4*)(w2d + kc * 4);
        q0 = fmaf(u.x, wa.x, q0); q0 = fmaf(u.y, wa.y, q0); q0 = fmaf(u.z, wa.z, q0); q0 = fmaf(u.w, wa.w, q0);
        q1 = fmaf(u.x, wb.x, q1); q1 = fmaf(u.y, wb.y, q1); q1 = fmaf(u.z, wb.z, q1); q1 = fmaf(u.w, wb.w, q1);
        q2 = fmaf(u.x, wc4.x, q2); q2 = fmaf(u.y, wc4.y, q2); q2 = fmaf(u.z, wc4.z, q2); q2 = fmaf(u.w, wc4.w, q2);
        q3 = fmaf(u.x, wd.x, q3); q3 = fmaf(u.y, wd.y, q3); q3 = fmaf(u.z, wd.z, q3); q3 = fmaf(u.w, wd.w, q3);
    }
    const int g = base + nl;
    if (g < Nd)
        *(float4*)(hs2 + (size_t)g * 32 + mg * 4) = make_float4(q0, q1, q2, q3);
}

// ------------- sum 4 head partials -------------
__global__ __launch_bounds__(256) void combine_parts(
    const float* __restrict__ ap, float* __restrict__ o1, int N1,
    const float* __restrict__ bp, float* __restrict__ o2, int N2)
{
    int i = blockIdx.x * 256 + threadIdx.x;
    if (i < N1) {
        o1[i] = ap[i] + ap[N1 + i] + ap[2 * N1 + i] + ap[3 * N1 + i];
    } else {
        int j = i - N1;
        if (j < N2)
            o2[j] = bp[j] + bp[N2 + j] + bp[2 * N2 + j] + bp[3 * N2 + j];
    }
}

// ================= conv2: fused edge-softmax + aggregation + bias/ELU + classifier ==========
__global__ __launch_bounds__(256) void conv2_fused_kernel(const int* __restrict__ rowptr,
    const int* __restrict__ csr, const float* __restrict__ hs2,
    const float* __restrict__ als2, const float* __restrict__ ald2,
    const float* __restrict__ b2, const float* __restrict__ Wc, const float* __restrict__ bc,
    float* __restrict__ out, int Nd)
{
    int d = blockIdx.x * 4 + (threadIdx.x >> 6);
    int lane = threadIdx.x & 63;
    if (d >= Nd) return;
    int beg = rowptr[d], end = rowptr[d + 1];
    float aldd = ald2[d];
    int half = lane >> 5, c = lane & 31;
    float acc = 0.f, wsum = 0.f;
    for (int i = beg + half; i < end; i += 2) {
        int s = csr[i];
        float w = lrelu_exp(als2[s] + aldd);
        acc = fmaf(w, hs2[(size_t)s * 32 + c], acc);
        wsum += w;
    }
    acc  += __shfl_down(acc, 32);
    wsum += __shfl_down(wsum, 32);
    float val = 0.f;
    if (lane < 32) {
        float t2 = acc / (wsum + 1e-16f) + b2[c];
        t2 = t2 > 0.f ? t2 : (expf(t2) - 1.f);
        val = t2 * Wc[c];
    }
    #pragma unroll
    for (int o = 16; o > 0; o >>= 1) val += __shfl_down(val, o);
    if (lane == 0) out[d] = val + bc[0];
}

extern "C" void kernel_launch(void* const* d_in, const int* in_sizes, int n_in,
                              void* d_out, int out_size, void* d_ws, size_t ws_size,
                              hipStream_t stream)
{
    const float* x_tx    = (const float*)d_in[0];
    const float* x_user  = (const float*)d_in[1];
    const int*   ei_u2t  = (const int*)d_in[2];
    const int*   ei_t2u  = (const int*)d_in[3];
    const float* Wp_tx   = (const float*)d_in[4];
    const float* bp_tx   = (const float*)d_in[5];
    const float* Wp_user = (const float*)d_in[6];
    const float* bp_user = (const float*)d_in[7];
    const float* W1_u2t  = (const float*)d_in[8];
    const float* as1_u2t = (const float*)d_in[9];
    const float* ad1_u2t = (const float*)d_in[10];
    const float* b1_u2t  = (const float*)d_in[11];
    const float* W2_u2t  = (const float*)d_in[12];
    const float* as2_u2t = (const float*)d_in[13];
    const float* ad2_u2t = (const float*)d_in[14];
    const float* b2_u2t  = (const float*)d_in[15];
    const float* W1_t2u  = (const float*)d_in[16];
    const float* as1_t2u = (const float*)d_in[17];
    const float* ad1_t2u = (const float*)d_in[18];
    const float* b1_t2u  = (const float*)d_in[19];
    const float* Wc      = (const float*)d_in[24];
    const float* bc      = (const float*)d_in[25];
    float* out = (float*)d_out;
    float* ws  = (float*)d_ws;

    const int* src_u2t = ei_u2t;            // user ids
    const int* dst_u2t = ei_u2t + NE;       // tx ids
    const int* src_t2u = ei_t2u;            // tx ids
    const int* dst_u   = ei_t2u + NE;       // user ids

    // ---- workspace layout (floats) ----
    float* h_tx   = ws;                     //  6,400,000
    float* h_us   = ws + 6400000;           //  3,200,000 (ald2p/als2p alias after it dies)
    float* hs2    = ws + 9600000;           //  1,600,000
    float* als2   = ws + 11200000;          //     50,000
    float* ald2   = ws + 11250000;          //    100,000
    float* als_us = ws + 11350000;          //    200,000
    float* ald_us = ws + 11550000;          //    200,000
    float* als_tx = ws + 11750000;          //    400,000
    float* ald_tx = ws + 12150000;          //    400,000
    float* agg    = ws + 12550000;          // 25,600,000 (u2t then t2u, sequential)
    float* avec   = ws + 38150000;          //      1,536
    float* WT     = ws + 38151552;          //     40,960 (transposed weights)
    // partials alias dead h_us (dead after agg_conv1 u2t)
    float* ald2p = h_us;                    //    400,000 (4 x N_TX)
    float* als2p = h_us + 400000;           //    200,000 (4 x N_USER)
    // ---- int region ----
    int* ibase    = (int*)(ws + 38200000);
    int* deg_t    = ibase;                  //   100,000
    int* deg_u    = ibase + 100000;         //    50,000
    int* rowptr_t = ibase + 150000;         //   100,001
    int* cur_t    = ibase + 250001;         //   100,000
    int* csr_t    = ibase + 350001;         //   500,000
    int* rowptr_u = ibase + 850001;         //    50,001
    int* cur_u    = ibase + 900002;         //    50,000
    int* csr_u    = ibase + 950002;         //   500,000
    int* bsum_t   = ibase + 1450002;        //       512
    int* bsum_u   = ibase + 1450514;        //       512

    float* Msrc_u2t = avec + 0;
    float* Mdst_u2t = avec + 256;
    float* Msrc_t2u = avec + 512;
    float* Mdst_t2u = avec + 768;
    float* vsrc2    = avec + 1024;          // fold(W2, as2)
    float* vdst2    = avec + 1280;          // fold(W2, ad2)

    float* W1T_u2t = WT;
    float* W1T_t2u = WT + 16384;
    float* W2T     = WT + 32768;

    // ---- fold attention vectors into weights ----
    AVArgs6 av;
    av.t[0] = { W1_u2t, as1_u2t, Msrc_u2t, HID, NH, HID };
    av.t[1] = { W1_u2t, ad1_u2t, Mdst_u2t, HID, NH, HID };
    av.t[2] = { W1_t2u, as1_t2u, Msrc_t2u, HID, NH, HID };
    av.t[3] = { W1_t2u, ad1_t2u, Mdst_t2u, HID, NH, HID };
    av.t[4] = { W2_u2t, as2_u2t, vsrc2, HC1, 1, OUTC };
    av.t[5] = { W2_u2t, ad2_u2t, vdst2, HC1, 1, OUTC };
    attn_vecs_kernel<<<6, 256, 0, stream>>>(av);

    // ---- transpose weights for the reg-resident transforms ----
    prep_transpose<<<160, 256, 0, stream>>>(W1_u2t, W1_t2u, W2_u2t, WT);

    // ---- zero degree histograms ----
    hipMemsetAsync(deg_t, 0, 150000 * sizeof(int), stream);

    // ---- CSR build (both edge types, 5 launches) ----
    hist2_kernel<<<(2 * NE + 255) / 256, 256, 0, stream>>>(dst_u2t, dst_u, deg_t, deg_u);
    block_sum2_kernel<<<NB_T + NB_U, 256, 0, stream>>>(deg_t, bsum_t, deg_u, bsum_u);
    scan_bsum2_kernel<<<1, 512, 0, stream>>>(bsum_t, bsum_u);
    scan_final2_kernel<<<NB_T + NB_U, 256, 0, stream>>>(
        deg_t, bsum_t, rowptr_t, cur_t, deg_u, bsum_u, rowptr_u, cur_u);
    scatter2_kernel<<<(2 * NE + 255) / 256, 256, 0, stream>>>(
        src_u2t, dst_u2t, cur_t, csr_t, src_t2u, dst_u, cur_u, csr_u);

    // ---- input projections (measured-good tiled GEMM) ----
    gemm_kernel<<<dim3(1, (N_TX + 63) / 64), 256, 0, stream>>>(
        x_tx, Wp_tx, bp_tx, h_tx, N_TX, F_TX, HID, 1);
    gemm_kernel<<<dim3(1, (N_USER + 63) / 64), 256, 0, stream>>>(
        x_user, Wp_user, bp_user, h_us, N_USER, F_USER, HID, 1);

    // ---- node attention scalars (both node types, one launch) ----
    node_attn8_dual<<<(N_TX + N_USER) / 4, 256, 0, stream>>>(
        h_tx, Mdst_u2t, Msrc_t2u, ald_tx, als_tx,
        h_us, Msrc_u2t, Mdst_t2u, als_us, ald_us);

    // ================= conv1, u2t (dst = tx) =================
    agg_conv1_kernel<<<(N_TX + 3) / 4, 256, 0, stream>>>(
        rowptr_t, csr_t, h_us, als_us, ald_tx, agg, N_TX);
    transform_u2t_v4<<<N_TX / 32, 256, 0, stream>>>(
        agg, W1T_u2t, b1_u2t, vdst2, ald2p, N_TX);

    // ================= conv1, t2u (dst = user) + fused conv2 projection ==========
    agg_conv1_kernel<<<(N_USER + 3) / 4, 256, 0, stream>>>(
        rowptr_u, csr_u, h_tx, als_tx, ald_us, agg, N_USER);
    transform_t2u_v4<<<(N_USER + 31) / 32, 256, 0, stream>>>(
        agg, W1T_t2u, b1_t2u, vsrc2, W2T, als2p, hs2, N_USER);

    // ---- combine head partials ----
    combine_parts<<<(N_TX + N_USER + 255) / 256, 256, 0, stream>>>(
        ald2p, ald2, N_TX, als2p, als2, N_USER);

    // ================= conv2 + classifier =================
    conv2_fused_kernel<<<(N_TX + 3) / 4, 256, 0, stream>>>(
        rowptr_t, csr_t, hs2, als2, ald2, b2_u2t, Wc, bc, out, N_TX);
}

// Round 10
// 923.818 us; speedup vs baseline: 1.8813x; 1.3657x over previous
//
#include <hip/hip_runtime.h>
#include <hip/hip_bf16.h>
#include <math.h>

#define N_TX   100000
#define N_USER 50000
#define F_TX   128
#define F_USER 64
#define HID    64
#define NH     4
#define OUTC   32
#define NE     500000
#define HC1    256          // NH*HID
#define SLOPE  0.2f
#define NB_T   391          // (N_TX+255)/256
#define NB_U   196          // (N_USER+255)/256

__device__ __forceinline__ float elu_f(float x) { return x > 0.f ? x : (expf(x) - 1.f); }
__device__ __forceinline__ float lrelu_exp(float x) { x = x > 0.f ? x : SLOPE * x; return expf(x); }

// diagonal-swizzled index into the 256ch x 64node LDS tile (64 KiB exactly).
// conflict-free for: staging writes (lanes vary c), x-loads (lanes vary n, c fixed),
// u1 write-back (lanes vary n), phase-2 reads (lanes vary n).
#define SIDX(c, n) ((((c)) << 6) + ((((n) + ((c) >> 2))) & 63))

// ---- per-lane x row in 64 named scalars (demotion-safe: worst case = LDS re-read) ----
#define XL(i) const float X##i = sT[SIDX(hb + i, n)];
#define XLOAD_ALL \
    XL(0) XL(1) XL(2) XL(3) XL(4) XL(5) XL(6) XL(7) XL(8) XL(9) XL(10) XL(11) XL(12) XL(13) XL(14) XL(15) \
    XL(16) XL(17) XL(18) XL(19) XL(20) XL(21) XL(22) XL(23) XL(24) XL(25) XL(26) XL(27) XL(28) XL(29) XL(30) XL(31) \
    XL(32) XL(33) XL(34) XL(35) XL(36) XL(37) XL(38) XL(39) XL(40) XL(41) XL(42) XL(43) XL(44) XL(45) XL(46) XL(47) \
    XL(48) XL(49) XL(50) XL(51) XL(52) XL(53) XL(54) XL(55) XL(56) XL(57) XL(58) XL(59) XL(60) XL(61) XL(62) XL(63)

// 64 FMAs vs wave-uniform W row (SGPR operand), 4 independent chains
#define FJ(i, ch) ch = fmaf(X##i, wj[i], ch);
#define FMA_ALL \
    FJ(0,a0) FJ(1,a1) FJ(2,a2) FJ(3,a3) FJ(4,a0) FJ(5,a1) FJ(6,a2) FJ(7,a3) \
    FJ(8,a0) FJ(9,a1) FJ(10,a2) FJ(11,a3) FJ(12,a0) FJ(13,a1) FJ(14,a2) FJ(15,a3) \
    FJ(16,a0) FJ(17,a1) FJ(18,a2) FJ(19,a3) FJ(20,a0) FJ(21,a1) FJ(22,a2) FJ(23,a3) \
    FJ(24,a0) FJ(25,a1) FJ(26,a2) FJ(27,a3) FJ(28,a0) FJ(29,a1) FJ(30,a2) FJ(31,a3) \
    FJ(32,a0) FJ(33,a1) FJ(34,a2) FJ(35,a3) FJ(36,a0) FJ(37,a1) FJ(38,a2) FJ(39,a3) \
    FJ(40,a0) FJ(41,a1) FJ(42,a2) FJ(43,a3) FJ(44,a0) FJ(45,a1) FJ(46,a2) FJ(47,a3) \
    FJ(48,a0) FJ(49,a1) FJ(50,a2) FJ(51,a3) FJ(52,a0) FJ(53,a1) FJ(54,a2) FJ(55,a3) \
    FJ(56,a0) FJ(57,a1) FJ(58,a2) FJ(59,a3) FJ(60,a0) FJ(61,a1) FJ(62,a2) FJ(63,a3)

// ---------------- tiled fp32 GEMM: C = act(A[N,K] @ B[K,M] + bias) ----------------
__global__ __launch_bounds__(256) void gemm_kernel(const float* __restrict__ A,
    const float* __restrict__ B, const float* __restrict__ bias,
    float* __restrict__ C, int N, int K, int M, int act)
{
    __shared__ float As[16][65];
    __shared__ float Bs[16][65];
    const int tid = threadIdx.x;
    const int tx = tid % 16, ty = tid / 16;
    const int row0 = blockIdx.y * 64, col0 = blockIdx.x * 64;
    float acc[4][4] = {};
    for (int k0 = 0; k0 < K; k0 += 16) {
        #pragma unroll
        for (int i = 0; i < 4; ++i) {
            int idx = tid * 4 + i;           // 64x16 A tile
            int r = idx >> 4, kk = idx & 15;
            int gr = row0 + r;
            As[kk][r] = (gr < N) ? A[(size_t)gr * K + (k0 + kk)] : 0.f;
        }
        #pragma unroll
        for (int i = 0; i < 4; ++i) {
            int idx = tid * 4 + i;           // 16x64 B tile
            int kk = idx >> 6, c = idx & 63;
            int gc = col0 + c;
            Bs[kk][c] = (gc < M) ? B[(size_t)(k0 + kk) * M + gc] : 0.f;
        }
        __syncthreads();
        #pragma unroll
        for (int kk = 0; kk < 16; ++kk) {
            float a4[4], b4[4];
            #pragma unroll
            for (int i = 0; i < 4; ++i) a4[i] = As[kk][ty * 4 + i];
            #pragma unroll
            for (int j = 0; j < 4; ++j) b4[j] = Bs[kk][tx * 4 + j];
            #pragma unroll
            for (int i = 0; i < 4; ++i)
                #pragma unroll
                for (int j = 0; j < 4; ++j) acc[i][j] += a4[i] * b4[j];
        }
        __syncthreads();
    }
    #pragma unroll
    for (int i = 0; i < 4; ++i) {
        int r = row0 + ty * 4 + i;
        if (r >= N) continue;
        #pragma unroll
        for (int j = 0; j < 4; ++j) {
            int c = col0 + tx * 4 + j;
            if (c >= M) continue;
            float v = acc[i][j] + (bias ? bias[c] : 0.f);
            if (act == 1) v = elu_f(v);
            C[(size_t)r * M + c] = v;
        }
    }
}

// ------------- fold attention vectors into weights: Mv[k,h] = sum_c W[k,h*C+c]*a[h,c] -------------
struct AVArgs  { const float* W; const float* a; float* out; int K; int H; int C; };
struct AVArgs6 { AVArgs t[6]; };

__global__ void attn_vecs_kernel(AVArgs6 args)
{
    AVArgs A = args.t[blockIdx.x];
    int tid = threadIdx.x;
    if (tid < A.K * A.H) {
        int k = tid % A.K, h = tid / A.K;
        float s = 0.f;
        const float* wrow = A.W + (size_t)k * (A.H * A.C) + h * A.C;
        const float* arow = A.a + h * A.C;
        for (int c = 0; c < A.C; ++c) s += wrow[c] * arow[c];
        A.out[k * A.H + h] = s;
    }
}

// ------------- transpose W1 into row-contiguous-per-output layout -------------
// out: [0,16384) W1T_u2t[(h*64+j)*64+c] ; [16384,32768) W1T_t2u
__global__ __launch_bounds__(256) void prep_transpose(const float* __restrict__ W1a,
    const float* __restrict__ W1b, float* __restrict__ out)
{
    int i = blockIdx.x * 256 + threadIdx.x;
    if (i < 16384) {
        int hj = i >> 6, c = i & 63;
        out[i] = W1a[c * 256 + hj];
    } else if (i < 32768) {
        int k = i - 16384; int hj = k >> 6, c = k & 63;
        out[i] = W1b[c * 256 + hj];
    }
}

// ------------- per-node attention scalars for BOTH node types in one launch -------------
__global__ __launch_bounds__(256) void node_attn8_dual(
    const float* __restrict__ Xt, const float* __restrict__ Mta, const float* __restrict__ Mtb,
    float* __restrict__ ota, float* __restrict__ otb,
    const float* __restrict__ Xu, const float* __restrict__ Mua, const float* __restrict__ Mub,
    float* __restrict__ oua, float* __restrict__ oub)
{
    int wave = blockIdx.x * 4 + (threadIdx.x >> 6);
    int lane = threadIdx.x & 63;
    const float* X; const float* Ma; const float* Mb; float* oa; float* ob;
    if (wave < N_TX) {              // N_TX % 4 == 0 -> wave-uniform branch per block
        X = Xt + (size_t)wave * 64; Ma = Mta; Mb = Mtb;
        oa = ota + (size_t)wave * 4; ob = otb + (size_t)wave * 4;
    } else {
        int n = wave - N_TX;
        if (n >= N_USER) return;
        X = Xu + (size_t)n * 64; Ma = Mua; Mb = Mub;
        oa = oua + (size_t)n * 4; ob = oub + (size_t)n * 4;
    }
    float x = X[lane];
    float a0 = x * Ma[lane * 4 + 0];
    float a1 = x * Ma[lane * 4 + 1];
    float a2 = x * Ma[lane * 4 + 2];
    float a3 = x * Ma[lane * 4 + 3];
    float b0 = x * Mb[lane * 4 + 0];
    float b1 = x * Mb[lane * 4 + 1];
    float b2 = x * Mb[lane * 4 + 2];
    float b3 = x * Mb[lane * 4 + 3];
    for (int off = 32; off > 0; off >>= 1) {
        a0 += __shfl_down(a0, off); a1 += __shfl_down(a1, off);
        a2 += __shfl_down(a2, off); a3 += __shfl_down(a3, off);
        b0 += __shfl_down(b0, off); b1 += __shfl_down(b1, off);
        b2 += __shfl_down(b2, off); b3 += __shfl_down(b3, off);
    }
    if (lane == 0) {
        oa[0] = a0; oa[1] = a1; oa[2] = a2; oa[3] = a3;
        ob[0] = b0; ob[1] = b1; ob[2] = b2; ob[3] = b3;
    }
}

// ================= merged CSR build (both edge types per launch) =================
__global__ __launch_bounds__(256) void hist2_kernel(const int* __restrict__ dst_t,
    const int* __restrict__ dst_u, int* __restrict__ deg_t, int* __restrict__ deg_u)
{
    int e = blockIdx.x * 256 + threadIdx.x;
    if (e < NE) atomicAdd(&deg_t[dst_t[e]], 1);
    else {
        e -= NE;
        if (e < NE) atomicAdd(&deg_u[dst_u[e]], 1);
    }
}

__global__ __launch_bounds__(256) void block_sum2_kernel(const int* __restrict__ deg_t,
    int* __restrict__ bsum_t, const int* __restrict__ deg_u, int* __restrict__ bsum_u)
{
    __shared__ int lds[256];
    int b = blockIdx.x, t = threadIdx.x;
    const int* deg; int* bsum; int Nd, lb;
    if (b < NB_T) { deg = deg_t; bsum = bsum_t; Nd = N_TX; lb = b; }
    else         { deg = deg_u; bsum = bsum_u; Nd = N_USER; lb = b - NB_T; }
    int i = lb * 256 + t;
    lds[t] = (i < Nd) ? deg[i] : 0;
    __syncthreads();
    for (int o = 128; o > 0; o >>= 1) {
        if (t < o) lds[t] += lds[t + o];
        __syncthreads();
    }
    if (t == 0) bsum[lb] = lds[0];
}

__global__ __launch_bounds__(512) void scan_bsum2_kernel(int* __restrict__ bt,
    int* __restrict__ bu)
{
    __shared__ int lds[512];
    int t = threadIdx.x;
    {
        int v = (t < NB_T) ? bt[t] : 0;
        lds[t] = v;
        __syncthreads();
        for (int o = 1; o < 512; o <<= 1) {
            int x = (t >= o) ? lds[t - o] : 0;
            __syncthreads();
            lds[t] += x;
            __syncthreads();
        }
        if (t < NB_T) bt[t] = lds[t] - v;
        __syncthreads();
    }
    {
        int v = (t < NB_U) ? bu[t] : 0;
        lds[t] = v;
        __syncthreads();
        for (int o = 1; o < 512; o <<= 1) {
            int x = (t >= o) ? lds[t - o] : 0;
            __syncthreads();
            lds[t] += x;
            __syncthreads();
        }
        if (t < NB_U) bu[t] = lds[t] - v;
    }
}

__global__ __launch_bounds__(256) void scan_final2_kernel(
    const int* __restrict__ deg_t, const int* __restrict__ be_t,
    int* __restrict__ rowptr_t, int* __restrict__ cur_t,
    const int* __restrict__ deg_u, const int* __restrict__ be_u,
    int* __restrict__ rowptr_u, int* __restrict__ cur_u)
{
    __shared__ int lds[256];
    int b = blockIdx.x, t = threadIdx.x;
    const int* deg; const int* be; int* rowptr; int* cursor; int Nd, lb;
    if (b < NB_T) { deg = deg_t; be = be_t; rowptr = rowptr_t; cursor = cur_t; Nd = N_TX; lb = b; }
    else         { deg = deg_u; be = be_u; rowptr = rowptr_u; cursor = cur_u; Nd = N_USER; lb = b - NB_T; }
    int i = lb * 256 + t;
    int v = (i < Nd) ? deg[i] : 0;
    lds[t] = v;
    __syncthreads();
    for (int o = 1; o < 256; o <<= 1) {
        int x = (t >= o) ? lds[t - o] : 0;
        __syncthreads();
        lds[t] += x;
        __syncthreads();
    }
    int excl = lds[t] - v + be[lb];
    if (i < Nd) {
        rowptr[i] = excl;
        cursor[i] = excl;
        if (i == Nd - 1) rowptr[Nd] = NE;
    }
}

__global__ __launch_bounds__(256) void scatter2_kernel(
    const int* __restrict__ src_t, const int* __restrict__ dst_t,
    int* __restrict__ cur_t, int* __restrict__ csr_t,
    const int* __restrict__ src_u, const int* __restrict__ dst_u,
    int* __restrict__ cur_u, int* __restrict__ csr_u)
{
    int e = blockIdx.x * 256 + threadIdx.x;
    if (e < NE) {
        int p = atomicAdd(&cur_t[dst_t[e]], 1);
        csr_t[p] = src_t[e];
    } else {
        e -= NE;
        if (e < NE) {
            int p = atomicAdd(&cur_u[dst_u[e]], 1);
            csr_u[p] = src_u[e];
        }
    }
}

// ================= conv1 aggregation: one wave per dst node =================
__device__ __forceinline__ void acc_edge(int s, int lane,
    const float* __restrict__ als, const float* __restrict__ hsrc, const float4& A,
    float& a0, float& a1, float& a2, float& a3,
    float& w0, float& w1, float& w2, float& w3)
{
    float4 v = *(const float4*)(als + (size_t)s * 4);
    float x = hsrc[(size_t)s * 64 + lane];
    float e0 = lrelu_exp(v.x + A.x);
    float e1 = lrelu_exp(v.y + A.y);
    float e2 = lrelu_exp(v.z + A.z);
    float e3 = lrelu_exp(v.w + A.w);
    a0 = fmaf(e0, x, a0); w0 += e0;
    a1 = fmaf(e1, x, a1); w1 += e1;
    a2 = fmaf(e2, x, a2); w2 += e2;
    a3 = fmaf(e3, x, a3); w3 += e3;
}

__global__ __launch_bounds__(256) void agg_conv1_kernel(const int* __restrict__ rowptr,
    const int* __restrict__ csr, const float* __restrict__ hsrc,
    const float* __restrict__ als, const float* __restrict__ ald,
    float* __restrict__ agg, int Nd)
{
    int d = blockIdx.x * 4 + (threadIdx.x >> 6);
    int lane = threadIdx.x & 63;
    if (d >= Nd) return;
    int beg = rowptr[d], end = rowptr[d + 1];
    float4 A = *(const float4*)(ald + (size_t)d * 4);
    float a0 = 0.f, a1 = 0.f, a2 = 0.f, a3 = 0.f;
    float w0 = 0.f, w1 = 0.f, w2 = 0.f, w3 = 0.f;
    int i = beg;
    for (; i + 2 <= end; i += 2) {
        acc_edge(csr[i],     lane, als, hsrc, A, a0, a1, a2, a3, w0, w1, w2, w3);
        acc_edge(csr[i + 1], lane, als, hsrc, A, a0, a1, a2, a3, w0, w1, w2, w3);
    }
    if (i < end)
        acc_edge(csr[i], lane, als, hsrc, A, a0, a1, a2, a3, w0, w1, w2, w3);
    float* o = agg + (size_t)d * 256;
    o[lane]       = a0 / (w0 + 1e-16f);
    o[64 + lane]  = a1 / (w1 + 1e-16f);
    o[128 + lane] = a2 / (w2 + 1e-16f);
    o[192 + lane] = a3 / (w3 + 1e-16f);
}

// ---------- stage 64 agg rows into the swizzled LDS tile (coalesced reads) ----------
__device__ __forceinline__ void stage64(const float* __restrict__ agg, float* sT,
                                        int base, int Nd, int w, int lane)
{
    #pragma unroll 4
    for (int it = 0; it < 16; ++it) {
        int rl = w * 16 + it;
        int gr = base + rl; if (gr >= Nd) gr = Nd - 1;
        float4 v = *(const float4*)(agg + (size_t)gr * 256 + lane * 4);
        int c0 = lane * 4;
        sT[SIDX(c0 + 0, rl)] = v.x;
        sT[SIDX(c0 + 1, rl)] = v.y;
        sT[SIDX(c0 + 2, rl)] = v.z;
        sT[SIDX(c0 + 3, rl)] = v.w;
    }
}

// ================= conv1 u2t transform v5: lane=node, wave=head, W via scalar path ============
// ald2[d] = sum_h elu(agg_row_h @ W1_h + b1_h) . vvec_h   (t1 never stored)
__global__ __launch_bounds__(256, 2) void transform_u2t_v5(
    const float* __restrict__ agg, const float* __restrict__ W1T,
    const float* __restrict__ b1, const float* __restrict__ vvec,
    float* __restrict__ ald2, int Nd)
{
    __shared__ float sT[16384];         // 64 KiB
    const int tid = threadIdx.x;
    const int n = tid & 63;             // node within tile
    const int w = tid >> 6;             // head
    const int base = blockIdx.x * 64;
    const int hb = w << 6;
    const int hb_u = __builtin_amdgcn_readfirstlane(hb);

    stage64(agg, sT, base, Nd, w, n);
    __syncthreads();

    XLOAD_ALL;                          // own x row (head slice) -> 64 named scalars
    float dsum = 0.f;
    #pragma unroll 2
    for (int j = 0; j < 64; ++j) {
        const float* wj = W1T + ((hb_u + j) << 6);   // wave-uniform -> s_load path
        float a0 = b1[hb_u + j], a1 = 0.f, a2 = 0.f, a3 = 0.f;
        FMA_ALL;
        float v = (a0 + a1) + (a2 + a3);
        v = v > 0.f ? v : (expf(v) - 1.f);
        dsum = fmaf(v, vvec[hb_u + j], dsum);
    }
    __syncthreads();                    // x reads done -> reuse sT head for reduction
    sT[hb + n] = dsum;
    __syncthreads();
    if (tid < 64 && base + tid < Nd)
        ald2[base + tid] = sT[tid] + sT[64 + tid] + sT[128 + tid] + sT[192 + tid];
}

// ================= conv1 t2u transform v5 + fused conv2 projection ============
// phase 1: u1 written back into the LDS tile (own cells); dsum = u1_h . vvec_h
// phase 2: hs2[n,:32] = u1_row @ W2 (W2 rows wave-uniform -> scalar path)
#define QF(q, o) { q.x = fmaf(uk, wk[o], q.x); q.y = fmaf(uk, wk[o+1], q.y); \
                   q.z = fmaf(uk, wk[o+2], q.z); q.w = fmaf(uk, wk[o+3], q.w); }
__global__ __launch_bounds__(256, 2) void transform_t2u_v5(
    const float* __restrict__ agg, const float* __restrict__ W1T,
    const float* __restrict__ b1, const float* __restrict__ vvec,
    const float* __restrict__ W2, float* __restrict__ als2,
    float* __restrict__ hs2, int Nd)
{
    __shared__ float sT[16384];
    const int tid = threadIdx.x;
    const int n = tid & 63;
    const int w = tid >> 6;
    const int base = blockIdx.x * 64;
    const int hb = w << 6;
    const int hb_u = __builtin_amdgcn_readfirstlane(hb);

    stage64(agg, sT, base, Nd, w, n);
    __syncthreads();

    XLOAD_ALL;
    float dsum = 0.f;
    #pragma unroll 2
    for (int j = 0; j < 64; ++j) {
        const float* wj = W1T + ((hb_u + j) << 6);
        float a0 = b1[hb_u + j], a1 = 0.f, a2 = 0.f, a3 = 0.f;
        FMA_ALL;
        float v = (a0 + a1) + (a2 + a3);
        v = v > 0.f ? v : (expf(v) - 1.f);
        sT[SIDX(hb_u + j, n)] = v;      // u1 write-back (own cell; x already in regs)
        dsum = fmaf(v, vvec[hb_u + j], dsum);
    }
    __syncthreads();                    // all heads' u1 in tile

    // phase 2: lane=node computes all 32 hs2 cols; W2 row k wave-uniform
    float4 Q0 = {0,0,0,0}, Q1 = {0,0,0,0}, Q2 = {0,0,0,0}, Q3 = {0,0,0,0};
    float4 Q4 = {0,0,0,0}, Q5 = {0,0,0,0}, Q6 = {0,0,0,0}, Q7 = {0,0,0,0};
    #pragma unroll 4
    for (int k = 0; k < 256; ++k) {
        float uk = sT[SIDX(k, n)];
        const float* wk = W2 + (k << 5);
        QF(Q0, 0) QF(Q1, 4) QF(Q2, 8) QF(Q3, 12)
        QF(Q4, 16) QF(Q5, 20) QF(Q6, 24) QF(Q7, 28)
    }
    const int g = base + n;
    if (g < Nd) {
        float4* o = (float4*)(hs2 + (size_t)g * 32);
        o[0] = Q0; o[1] = Q1; o[2] = Q2; o[3] = Q3;
        o[4] = Q4; o[5] = Q5; o[6] = Q6; o[7] = Q7;
    }
    __syncthreads();                    // phase-2 reads done -> reuse sT head
    sT[hb + n] = dsum;
    __syncthreads();
    if (tid < 64 && base + tid < Nd)
        als2[base + tid] = sT[tid] + sT[64 + tid] + sT[128 + tid] + sT[192 + tid];
}

// ================= conv2: fused edge-softmax + aggregation + bias/ELU + classifier ==========
__global__ __launch_bounds__(256) void conv2_fused_kernel(const int* __restrict__ rowptr,
    const int* __restrict__ csr, const float* __restrict__ hs2,
    const float* __restrict__ als2, const float* __restrict__ ald2,
    const float* __restrict__ b2, const float* __restrict__ Wc, const float* __restrict__ bc,
    float* __restrict__ out, int Nd)
{
    int d = blockIdx.x * 4 + (threadIdx.x >> 6);
    int lane = threadIdx.x & 63;
    if (d >= Nd) return;
    int beg = rowptr[d], end = rowptr[d + 1];
    float aldd = ald2[d];
    int half = lane >> 5, c = lane & 31;
    float acc = 0.f, wsum = 0.f;
    for (int i = beg + half; i < end; i += 2) {
        int s = csr[i];
        float w = lrelu_exp(als2[s] + aldd);
        acc = fmaf(w, hs2[(size_t)s * 32 + c], acc);
        wsum += w;
    }
    acc  += __shfl_down(acc, 32);
    wsum += __shfl_down(wsum, 32);
    float val = 0.f;
    if (lane < 32) {
        float t2 = acc / (wsum + 1e-16f) + b2[c];
        t2 = t2 > 0.f ? t2 : (expf(t2) - 1.f);
        val = t2 * Wc[c];
    }
    #pragma unroll
    for (int o = 16; o > 0; o >>= 1) val += __shfl_down(val, o);
    if (lane == 0) out[d] = val + bc[0];
}

extern "C" void kernel_launch(void* const* d_in, const int* in_sizes, int n_in,
                              void* d_out, int out_size, void* d_ws, size_t ws_size,
                              hipStream_t stream)
{
    const float* x_tx    = (const float*)d_in[0];
    const float* x_user  = (const float*)d_in[1];
    const int*   ei_u2t  = (const int*)d_in[2];
    const int*   ei_t2u  = (const int*)d_in[3];
    const float* Wp_tx   = (const float*)d_in[4];
    const float* bp_tx   = (const float*)d_in[5];
    const float* Wp_user = (const float*)d_in[6];
    const float* bp_user = (const float*)d_in[7];
    const float* W1_u2t  = (const float*)d_in[8];
    const float* as1_u2t = (const float*)d_in[9];
    const float* ad1_u2t = (const float*)d_in[10];
    const float* b1_u2t  = (const float*)d_in[11];
    const float* W2_u2t  = (const float*)d_in[12];
    const float* as2_u2t = (const float*)d_in[13];
    const float* ad2_u2t = (const float*)d_in[14];
    const float* b2_u2t  = (const float*)d_in[15];
    const float* W1_t2u  = (const float*)d_in[16];
    const float* as1_t2u = (const float*)d_in[17];
    const float* ad1_t2u = (const float*)d_in[18];
    const float* b1_t2u  = (const float*)d_in[19];
    const float* Wc      = (const float*)d_in[24];
    const float* bc      = (const float*)d_in[25];
    float* out = (float*)d_out;
    float* ws  = (float*)d_ws;

    const int* src_u2t = ei_u2t;            // user ids
    const int* dst_u2t = ei_u2t + NE;       // tx ids
    const int* src_t2u = ei_t2u;            // tx ids
    const int* dst_u   = ei_t2u + NE;       // user ids

    // ---- workspace layout (floats) ----
    float* h_tx   = ws;                     //  6,400,000
    float* h_us   = ws + 6400000;           //  3,200,000
    float* hs2    = ws + 9600000;           //  1,600,000
    float* als2   = ws + 11200000;          //     50,000
    float* ald2   = ws + 11250000;          //    100,000
    float* als_us = ws + 11350000;          //    200,000
    float* ald_us = ws + 11550000;          //    200,000
    float* als_tx = ws + 11750000;          //    400,000
    float* ald_tx = ws + 12150000;          //    400,000
    float* agg    = ws + 12550000;          // 25,600,000 (u2t then t2u, sequential)
    float* avec   = ws + 38150000;          //      1,536
    float* WT     = ws + 38151552;          //     32,768 (transposed W1 x2)
    // ---- int region ----
    int* ibase    = (int*)(ws + 38190000);
    int* deg_t    = ibase;                  //   100,000
    int* deg_u    = ibase + 100000;         //    50,000
    int* rowptr_t = ibase + 150000;         //   100,001
    int* cur_t    = ibase + 250001;         //   100,000
    int* csr_t    = ibase + 350001;         //   500,000
    int* rowptr_u = ibase + 850001;         //    50,001
    int* cur_u    = ibase + 900002;         //    50,000
    int* csr_u    = ibase + 950002;         //   500,000
    int* bsum_t   = ibase + 1450002;        //       512
    int* bsum_u   = ibase + 1450514;        //       512

    float* Msrc_u2t = avec + 0;
    float* Mdst_u2t = avec + 256;
    float* Msrc_t2u = avec + 512;
    float* Mdst_t2u = avec + 768;
    float* vsrc2    = avec + 1024;          // fold(W2, as2): als2 = u1 . vsrc2
    float* vdst2    = avec + 1280;          // fold(W2, ad2): ald2 = t1 . vdst2

    float* W1T_u2t = WT;
    float* W1T_t2u = WT + 16384;

    // ---- fold attention vectors into weights ----
    AVArgs6 av;
    av.t[0] = { W1_u2t, as1_u2t, Msrc_u2t, HID, NH, HID };
    av.t[1] = { W1_u2t, ad1_u2t, Mdst_u2t, HID, NH, HID };
    av.t[2] = { W1_t2u, as1_t2u, Msrc_t2u, HID, NH, HID };
    av.t[3] = { W1_t2u, ad1_t2u, Mdst_t2u, HID, NH, HID };
    av.t[4] = { W2_u2t, as2_u2t, vsrc2, HC1, 1, OUTC };
    av.t[5] = { W2_u2t, ad2_u2t, vdst2, HC1, 1, OUTC };
    attn_vecs_kernel<<<6, 256, 0, stream>>>(av);

    // ---- transpose W1 for the scalar-path transforms ----
    prep_transpose<<<128, 256, 0, stream>>>(W1_u2t, W1_t2u, WT);

    // ---- zero degree histograms ----
    hipMemsetAsync(deg_t, 0, 150000 * sizeof(int), stream);

    // ---- CSR build (both edge types, 5 launches) ----
    hist2_kernel<<<(2 * NE + 255) / 256, 256, 0, stream>>>(dst_u2t, dst_u, deg_t, deg_u);
    block_sum2_kernel<<<NB_T + NB_U, 256, 0, stream>>>(deg_t, bsum_t, deg_u, bsum_u);
    scan_bsum2_kernel<<<1, 512, 0, stream>>>(bsum_t, bsum_u);
    scan_final2_kernel<<<NB_T + NB_U, 256, 0, stream>>>(
        deg_t, bsum_t, rowptr_t, cur_t, deg_u, bsum_u, rowptr_u, cur_u);
    scatter2_kernel<<<(2 * NE + 255) / 256, 256, 0, stream>>>(
        src_u2t, dst_u2t, cur_t, csr_t, src_t2u, dst_u, cur_u, csr_u);

    // ---- input projections (measured-good tiled GEMM) ----
    gemm_kernel<<<dim3(1, (N_TX + 63) / 64), 256, 0, stream>>>(
        x_tx, Wp_tx, bp_tx, h_tx, N_TX, F_TX, HID, 1);
    gemm_kernel<<<dim3(1, (N_USER + 63) / 64), 256, 0, stream>>>(
        x_user, Wp_user, bp_user, h_us, N_USER, F_USER, HID, 1);

    // ---- node attention scalars (both node types, one launch) ----
    node_attn8_dual<<<(N_TX + N_USER) / 4, 256, 0, stream>>>(
        h_tx, Mdst_u2t, Msrc_t2u, ald_tx, als_tx,
        h_us, Msrc_u2t, Mdst_t2u, als_us, ald_us);

    // ================= conv1, u2t (dst = tx) =================
    agg_conv1_kernel<<<(N_TX + 3) / 4, 256, 0, stream>>>(
        rowptr_t, csr_t, h_us, als_us, ald_tx, agg, N_TX);
    transform_u2t_v5<<<(N_TX + 63) / 64, 256, 0, stream>>>(
        agg, W1T_u2t, b1_u2t, vdst2, ald2, N_TX);

    // ================= conv1, t2u (dst = user) + fused conv2 projection ==========
    agg_conv1_kernel<<<(N_USER + 3) / 4, 256, 0, stream>>>(
        rowptr_u, csr_u, h_tx, als_tx, ald_us, agg, N_USER);
    transform_t2u_v5<<<(N_USER + 63) / 64, 256, 0, stream>>>(
        agg, W1T_t2u, b1_t2u, vsrc2, W2_u2t, als2, hs2, N_USER);

    // ================= conv2 + classifier =================
    conv2_fused_kernel<<<(N_TX + 3) / 4, 256, 0, stream>>>(
        rowptr_t, csr_t, hs2, als2, ald2, b2_u2t, Wc, bc, out, N_TX);
}